// Round 3
// baseline (424.176 us; speedup 1.0000x reference)
//
#include <hip/hip_runtime.h>
#include <stdint.h>

#define K_DIM 4096
#define N_DIM 11008
#define WORDS_N 1376          // N_DIM / 8 packed words
#define BM 128
#define BN 128
#define BK 64
#define ASTR 72               // As row stride in fp16 elems (pad breaks pow2 bank pattern)

typedef _Float16 f16x8 __attribute__((ext_vector_type(8)));
typedef float    f32x4 __attribute__((ext_vector_type(4)));
typedef float    f32x8 __attribute__((ext_vector_type(8)));
typedef int      int4v __attribute__((ext_vector_type(4)));

__global__ __launch_bounds__(256, 2)
void awq_gemm_kernel(const float* __restrict__ x,
                     const int* __restrict__ qw,
                     const int* __restrict__ qz,
                     const float* __restrict__ sc,
                     const float* __restrict__ bias,
                     float* __restrict__ out,
                     int M)
{
    __shared__ __align__(16) _Float16 As[BM * ASTR];  // 18432 B
    __shared__ __align__(16) int Wq[16 * BK];         // [word][k] transposed, 4096 B

    const int tid  = threadIdx.x;
    const int lane = tid & 63;
    const int wid  = tid >> 6;

    const int bn0 = blockIdx.x * BN;
    const int bm0 = blockIdx.y * BM;
    const int w0  = bn0 >> 3;            // first packed word col of this tile

    // 2x2 waves, each owns a 64x64 output sub-tile
    const int wm0 = (wid >> 1) * 64;
    const int wn0 = (wid & 1) * 64;

    // A staging: 4 rows of 8 floats per thread
    const int a_row = tid >> 3;          // 0..31 (+32*i)
    const int a_col = (tid & 7) * 8;     // 0..56

    // B raw staging: each thread one dwordx4 (4 consecutive words, one k-row)
    const int b_krow = tid >> 2;         // 0..63
    const int b_wq   = (tid & 3) * 4;    // 0,4,8,12

    // per-bn column constants for this lane (AWQ interleave vs ORDER_SHIFTS verified)
    int n_loc[4], w_loc[4], shf[4];
    #pragma unroll
    for (int bn = 0; bn < 4; ++bn) {
        n_loc[bn] = wn0 + bn * 16 + (lane & 15);     // 0..127 within tile
        w_loc[bn] = n_loc[bn] >> 3;                  // 0..15
        int j = n_loc[bn] & 7;
        shf[bn] = ((j & 1) << 4) + ((j >> 1) << 2);  // j -> [0,16,4,20,8,24,12,28]
    }

    float s_f[4], zs[4];

    f32x4 acc[4][4];
    #pragma unroll
    for (int i = 0; i < 4; ++i)
        #pragma unroll
        for (int j = 0; j < 4; ++j)
            acc[i][j] = (f32x4){0.f, 0.f, 0.f, 0.f};

    f32x8 aReg[4];
    int4v bReg;

#define LOAD_TILE(K0)                                                              \
    {                                                                              \
        _Pragma("unroll")                                                          \
        for (int i = 0; i < 4; ++i) {                                              \
            int row = bm0 + a_row + i * 32;                                        \
            if (row < M)                                                           \
                aReg[i] = *(const f32x8*)(x + (size_t)row * K_DIM + (K0) + a_col); \
            else                                                                   \
                aReg[i] = (f32x8){0.f,0.f,0.f,0.f,0.f,0.f,0.f,0.f};                \
        }                                                                          \
        bReg = *(const int4v*)(qw + (size_t)((K0) + b_krow) * WORDS_N + w0 + b_wq);\
    }

    LOAD_TILE(0);

    const int NT = K_DIM / BK;  // 64
    for (int t = 0; t < NT; ++t) {
        const int k0 = t * BK;

        __syncthreads();   // previous iteration done reading LDS
        #pragma unroll
        for (int i = 0; i < 4; ++i) {
            f16x8 h;
            #pragma unroll
            for (int r = 0; r < 8; ++r) h[r] = (_Float16)aReg[i][r];
            *(f16x8*)&As[(a_row + i * 32) * ASTR + a_col] = h;
        }
        #pragma unroll
        for (int c = 0; c < 4; ++c)
            Wq[(b_wq + c) * BK + b_krow] = bReg[c];   // transposed: Wq[w][k]
        __syncthreads();   // tile visible

        if (t + 1 < NT) LOAD_TILE(k0 + BK);   // prefetch next tile into regs

        if ((t & 1) == 0) {   // group changes every 2 tiles (GROUP=128, BK=64)
            const int g = k0 >> 7;
            #pragma unroll
            for (int bn = 0; bn < 4; ++bn) {
                s_f[bn] = sc[(size_t)g * N_DIM + bn0 + n_loc[bn]];
                int zq  = (qz[(size_t)g * WORDS_N + w0 + w_loc[bn]] >> shf[bn]) & 0xF;
                zs[bn]  = (float)zq * s_f[bn];
            }
        }

        #pragma unroll
        for (int ks = 0; ks < 2; ++ks) {
            const int kk = ks * 32 + (lane >> 4) * 8;   // this lane's k-octet
            f16x8 af[4];
            #pragma unroll
            for (int am = 0; am < 4; ++am)
                af[am] = *(const f16x8*)&As[(wm0 + am * 16 + (lane & 15)) * ASTR + kk];

            #pragma unroll
            for (int bn = 0; bn < 4; ++bn) {
                const int4v lo = *(const int4v*)&Wq[w_loc[bn] * BK + kk];
                const int4v hi = *(const int4v*)&Wq[w_loc[bn] * BK + kk + 4];
                f16x8 bfrag;
                #pragma unroll
                for (int r = 0; r < 4; ++r) {
                    int q = (lo[r] >> shf[bn]) & 0xF;
                    bfrag[r] = (_Float16)((float)q * s_f[bn] - zs[bn]);
                }
                #pragma unroll
                for (int r = 0; r < 4; ++r) {
                    int q = (hi[r] >> shf[bn]) & 0xF;
                    bfrag[4 + r] = (_Float16)((float)q * s_f[bn] - zs[bn]);
                }
                #pragma unroll
                for (int am = 0; am < 4; ++am)
                    acc[am][bn] = __builtin_amdgcn_mfma_f32_16x16x32_f16(
                        af[am], bfrag, acc[am][bn], 0, 0, 0);
            }
        }
    }

    // epilogue: C/D layout col=lane&15, row=(lane>>4)*4+r (m89-verified)
    #pragma unroll
    for (int bn = 0; bn < 4; ++bn) {
        const int col = bn0 + wn0 + bn * 16 + (lane & 15);
        const float b_f = bias[col];
        #pragma unroll
        for (int am = 0; am < 4; ++am) {
            const int row_base = bm0 + wm0 + am * 16 + ((lane >> 4) << 2);
            #pragma unroll
            for (int r = 0; r < 4; ++r) {
                const int row = row_base + r;
                if (row < M)
                    out[(size_t)row * N_DIM + col] = acc[am][bn][r] + b_f;
            }
        }
    }
#undef LOAD_TILE
}

extern "C" void kernel_launch(void* const* d_in, const int* in_sizes, int n_in,
                              void* d_out, int out_size, void* d_ws, size_t ws_size,
                              hipStream_t stream) {
    const float* x    = (const float*)d_in[0];
    const int*   qw   = (const int*)d_in[1];
    const int*   qz   = (const int*)d_in[2];
    const float* sc   = (const float*)d_in[3];
    const float* bias = (const float*)d_in[4];
    float*       out  = (float*)d_out;

    const int M = in_sizes[0] / K_DIM;   // 2048 tokens
    dim3 grid(N_DIM / BN, (M + BM - 1) / BM);
    awq_gemm_kernel<<<grid, dim3(256), 0, stream>>>(x, qw, qz, sc, bias, out, M);
}

// Round 5
// 284.241 us; speedup vs baseline: 1.4923x; 1.4923x over previous
//
#include <hip/hip_runtime.h>
#include <stdint.h>

#define K_DIM 4096
#define N_DIM 11008
#define WORDS_N 1376          // N_DIM / 8 packed words
#define BM 128
#define BN 128
#define BK 64
#define ASTR 72               // As row stride in fp16 elems (144B; 2-way bank alias = free)
#define WSTR 68               // Wq row stride in ints (272B: 16B-aligned, bank-spread)

typedef _Float16 f16x2 __attribute__((ext_vector_type(2)));
typedef _Float16 f16x8 __attribute__((ext_vector_type(8)));
typedef float    f32x4 __attribute__((ext_vector_type(4)));
typedef float    f32x8 __attribute__((ext_vector_type(8)));
typedef int      int4v __attribute__((ext_vector_type(4)));
typedef unsigned int u32;

// two packed-word k-values -> half2 of dequantized weights for one column
// (q-z)*s computed as pk_fma(q, s, -zs); q built exactly via 0x6400 magic + pk_add(-1024)
__device__ __forceinline__ f16x2 dq2(int wa, int wb, int shf, f16x2 s2, f16x2 c2) {
    u32 t0 = ((u32)wa >> shf) & 0xFu;
    u32 t1 = ((u32)wb >> shf) & 0xFu;
    u32 h  = 0x64006400u | t0 | (t1 << 16);
    f16x2 q = __builtin_bit_cast(f16x2, h);
    q = q - (f16x2)((_Float16)1024.0f);   // exact: (1024+q) - 1024
    return q * s2 + c2;                    // v_pk_fma_f16
}

__global__ __launch_bounds__(256, 2)
void awq_gemm_kernel(const float* __restrict__ x,
                     const int* __restrict__ qw,
                     const int* __restrict__ qz,
                     const float* __restrict__ sc,
                     const float* __restrict__ bias,
                     float* __restrict__ out,
                     int M)
{
    __shared__ __align__(16) _Float16 As[BM * ASTR];  // 18432 B
    __shared__ __align__(16) int Wq[16 * WSTR];       // [word][k] transposed, 4352 B

    const int tid  = threadIdx.x;
    const int lane = tid & 63;
    const int wid  = tid >> 6;

    const int bn0 = blockIdx.x * BN;
    const int bm0 = blockIdx.y * BM;
    const int w0  = bn0 >> 3;

    // 1x4 wave grid: each wave owns all 128 rows x 32 distinct cols -> zero
    // dequant redundancy across waves
    const int wn0 = wid * 32;

    // A staging: 4 rows of 8 floats per thread
    const int a_row = tid >> 3;          // 0..31 (+32*i)
    const int a_col = (tid & 7) * 8;

    // B raw staging: each thread one dwordx4 (4 consecutive words, one k-row)
    const int b_krow = tid >> 2;         // 0..63
    const int b_wq   = (tid & 3) * 4;    // 0,4,8,12

    // per-bn column constants for this lane (AWQ interleave vs ORDER_SHIFTS verified)
    int n_loc[2], w_loc[2], shf[2];
    #pragma unroll
    for (int bn = 0; bn < 2; ++bn) {
        n_loc[bn] = wn0 + bn * 16 + (lane & 15);
        w_loc[bn] = n_loc[bn] >> 3;
        int j = n_loc[bn] & 7;
        shf[bn] = ((j & 1) << 4) + ((j >> 1) << 2);  // j -> [0,16,4,20,8,24,12,28]
    }

    f16x2 s2[2], c2[2];   // scale (replicated) and -(z*s) per owned column

    f32x4 acc[8][2];
    #pragma unroll
    for (int i = 0; i < 8; ++i)
        #pragma unroll
        for (int j = 0; j < 2; ++j)
            acc[i][j] = (f32x4){0.f, 0.f, 0.f, 0.f};

    f32x8 aReg[4];
    int4v bReg;

#define LOAD_TILE(K0)                                                              \
    {                                                                              \
        _Pragma("unroll")                                                          \
        for (int i = 0; i < 4; ++i) {                                              \
            int row = bm0 + a_row + i * 32;                                        \
            if (row < M)                                                           \
                aReg[i] = *(const f32x8*)(x + (size_t)row * K_DIM + (K0) + a_col); \
            else                                                                   \
                aReg[i] = (f32x8){0.f,0.f,0.f,0.f,0.f,0.f,0.f,0.f};                \
        }                                                                          \
        bReg = *(const int4v*)(qw + (size_t)((K0) + b_krow) * WORDS_N + w0 + b_wq);\
    }

    LOAD_TILE(0);

    const int NT = K_DIM / BK;  // 64
    for (int t = 0; t < NT; ++t) {
        const int k0 = t * BK;

        __syncthreads();   // previous iteration done reading LDS
        #pragma unroll
        for (int i = 0; i < 4; ++i) {
            f16x8 h;
            #pragma unroll
            for (int r = 0; r < 4; ++r) {
                f16x2 p = __builtin_bit_cast(f16x2,
                    __builtin_amdgcn_cvt_pkrtz(aReg[i][2*r], aReg[i][2*r+1])); // exact: x is fp16-valued
                h[2*r]   = p[0];
                h[2*r+1] = p[1];
            }
            *(f16x8*)&As[(a_row + i * 32) * ASTR + a_col] = h;
        }
        #pragma unroll
        for (int c = 0; c < 4; ++c)
            Wq[(b_wq + c) * WSTR + b_krow] = bReg[c];   // transposed: Wq[w][k]
        __syncthreads();   // tile visible

        if (t + 1 < NT) LOAD_TILE(k0 + BK);   // prefetch next tile into regs

        if ((t & 1) == 0) {   // group changes every 2 tiles (GROUP=128, BK=64)
            const int g = k0 >> 7;
            #pragma unroll
            for (int bn = 0; bn < 2; ++bn) {
                float s = sc[(size_t)g * N_DIM + bn0 + n_loc[bn]];
                int zq  = (qz[(size_t)g * WORDS_N + w0 + w_loc[bn]] >> shf[bn]) & 0xF;
                _Float16 sh = (_Float16)s;
                _Float16 nz = (_Float16)(-(float)zq * s);   // |z*s| <= 0.17: fp16 rounding err ~4e-5
                s2[bn] = (f16x2){sh, sh};
                c2[bn] = (f16x2){nz, nz};
            }
        }

        #pragma unroll
        for (int ks = 0; ks < 2; ++ks) {
            const int kk = ks * 32 + (lane >> 4) * 8;   // this lane's k-octet
            f16x8 af[8];
            #pragma unroll
            for (int am = 0; am < 8; ++am)
                af[am] = *(const f16x8*)&As[(am * 16 + (lane & 15)) * ASTR + kk];

            #pragma unroll
            for (int bn = 0; bn < 2; ++bn) {
                const int4v lo = *(const int4v*)&Wq[w_loc[bn] * WSTR + kk];
                const int4v hi = *(const int4v*)&Wq[w_loc[bn] * WSTR + kk + 4];
                f16x8 bf;
                f16x2 p;
                p = dq2(lo[0], lo[1], shf[bn], s2[bn], c2[bn]); bf[0]=p[0]; bf[1]=p[1];
                p = dq2(lo[2], lo[3], shf[bn], s2[bn], c2[bn]); bf[2]=p[0]; bf[3]=p[1];
                p = dq2(hi[0], hi[1], shf[bn], s2[bn], c2[bn]); bf[4]=p[0]; bf[5]=p[1];
                p = dq2(hi[2], hi[3], shf[bn], s2[bn], c2[bn]); bf[6]=p[0]; bf[7]=p[1];
                #pragma unroll
                for (int am = 0; am < 8; ++am)
                    acc[am][bn] = __builtin_amdgcn_mfma_f32_16x16x32_f16(
                        af[am], bf, acc[am][bn], 0, 0, 0);
            }
        }
    }

    // epilogue: C/D layout col=lane&15, row=(lane>>4)*4+r (m89-verified)
    #pragma unroll
    for (int bn = 0; bn < 2; ++bn) {
        const int col = bn0 + wn0 + bn * 16 + (lane & 15);
        const float b_f = bias[col];
        #pragma unroll
        for (int am = 0; am < 8; ++am) {
            const int row_base = bm0 + am * 16 + ((lane >> 4) << 2);
            #pragma unroll
            for (int r = 0; r < 4; ++r) {
                const int row = row_base + r;
                if (row < M)
                    out[(size_t)row * N_DIM + col] = acc[am][bn][r] + b_f;
            }
        }
    }
#undef LOAD_TILE
}

extern "C" void kernel_launch(void* const* d_in, const int* in_sizes, int n_in,
                              void* d_out, int out_size, void* d_ws, size_t ws_size,
                              hipStream_t stream) {
    const float* x    = (const float*)d_in[0];
    const int*   qw   = (const int*)d_in[1];
    const int*   qz   = (const int*)d_in[2];
    const float* sc   = (const float*)d_in[3];
    const float* bias = (const float*)d_in[4];
    float*       out  = (float*)d_out;

    const int M = in_sizes[0] / K_DIM;   // 2048 tokens
    dim3 grid(N_DIM / BN, (M + BM - 1) / BM);
    awq_gemm_kernel<<<grid, dim3(256), 0, stream>>>(x, qw, qz, sc, bias, out, M);
}

// Round 6
// 274.800 us; speedup vs baseline: 1.5436x; 1.0344x over previous
//
#include <hip/hip_runtime.h>
#include <stdint.h>

#define K_DIM 4096
#define N_DIM 11008
#define WORDS_N 1376          // N_DIM / 8 packed words
#define BM 128
#define BN 128
#define BK 64
#define ASTR 72               // As row stride in fp16 elems (144B; balanced b128 access)
#define WSTR 68               // Wq row stride in ints (272B: 16B-aligned, bank-spread)

typedef _Float16 f16x2 __attribute__((ext_vector_type(2)));
typedef _Float16 f16x8 __attribute__((ext_vector_type(8)));
typedef float    f32x4 __attribute__((ext_vector_type(4)));
typedef float    f32x8 __attribute__((ext_vector_type(8)));
typedef int      int4v __attribute__((ext_vector_type(4)));
typedef unsigned short ushort;
typedef unsigned int u32;

// two packed-word k-values -> half2 of dequantized weights for one column
// (q-z)*s via pk_fma(q, s, -zs); q built exactly via 0x6400 magic + pk_sub(1024)
__device__ __forceinline__ f16x2 dq2(int wa, int wb, int shf, f16x2 s2, f16x2 c2) {
    u32 t0 = ((u32)wa >> shf) & 0xFu;
    u32 t1 = ((u32)wb >> shf) & 0xFu;
    u32 h  = 0x64006400u | t0 | (t1 << 16);
    f16x2 q = __builtin_bit_cast(f16x2, h);
    q = q - (f16x2)((_Float16)1024.0f);   // exact: (1024+q) - 1024
    return q * s2 + c2;                    // v_pk_fma_f16
}

// ---- pre-pass: x f32 -> fp16 (values are exactly fp16-representable) ----
__global__ __launch_bounds__(256)
void cvt_x_kernel(const float* __restrict__ x, ushort* __restrict__ xf, int n8) {
    for (int i = blockIdx.x * 256 + threadIdx.x; i < n8; i += gridDim.x * 256) {
        f32x4 a = *(const f32x4*)(x + (size_t)i * 8);
        f32x4 b = *(const f32x4*)(x + (size_t)i * 8 + 4);
        int4v o;
        o[0] = __builtin_bit_cast(int, __builtin_amdgcn_cvt_pkrtz(a[0], a[1]));
        o[1] = __builtin_bit_cast(int, __builtin_amdgcn_cvt_pkrtz(a[2], a[3]));
        o[2] = __builtin_bit_cast(int, __builtin_amdgcn_cvt_pkrtz(b[0], b[1]));
        o[3] = __builtin_bit_cast(int, __builtin_amdgcn_cvt_pkrtz(b[2], b[3]));
        *(int4v*)(xf + (size_t)i * 8) = o;
    }
}

template <bool XF16>
__global__ __launch_bounds__(256, 3)
void awq_gemm_kernel(const void* __restrict__ xin,
                     const int* __restrict__ qw,
                     const int* __restrict__ qz,
                     const float* __restrict__ sc,
                     const float* __restrict__ bias,
                     float* __restrict__ out,
                     int M)
{
    __shared__ __align__(16) _Float16 As[BM * ASTR];  // 18432 B
    __shared__ __align__(16) int Wq[16 * WSTR];       // [word][k] transposed, 4352 B

    const int tid  = threadIdx.x;
    const int lane = tid & 63;
    const int wid  = tid >> 6;

    const int bn0 = blockIdx.x * BN;
    const int bm0 = blockIdx.y * BM;
    const int w0  = bn0 >> 3;

    // 1x4 wave grid: each wave owns all 128 rows x 32 distinct cols
    const int wn0 = wid * 32;

    // A staging: 4 rows of 8 fp16 (or 8 f32) per thread
    const int a_row = tid >> 3;          // 0..31 (+32*i)
    const int a_col = (tid & 7) * 8;

    // B raw staging: each thread one dwordx4 (4 consecutive words, one k-row)
    const int b_krow = tid >> 2;         // 0..63
    const int b_wq   = (tid & 3) * 4;    // 0,4,8,12

    // per-bn column constants (AWQ interleave vs ORDER_SHIFTS verified)
    int n_loc[2], w_loc[2], shf[2];
    #pragma unroll
    for (int bn = 0; bn < 2; ++bn) {
        n_loc[bn] = wn0 + bn * 16 + (lane & 15);
        w_loc[bn] = n_loc[bn] >> 3;
        int j = n_loc[bn] & 7;
        shf[bn] = ((j & 1) << 4) + ((j >> 1) << 2);  // j -> [0,16,4,20,8,24,12,28]
    }

    f16x2 s2[2], c2[2];   // scale and -(z*s) per owned column

    f32x4 acc[8][2];
    #pragma unroll
    for (int i = 0; i < 8; ++i)
        #pragma unroll
        for (int j = 0; j < 2; ++j)
            acc[i][j] = (f32x4){0.f, 0.f, 0.f, 0.f};

    int4v aReg16[4];
    f32x8 aReg32[4];
    int4v bReg;

    const ushort* x16 = (const ushort*)xin;
    const float*  x32 = (const float*)xin;

#define LOAD_TILE(K0)                                                                  \
    {                                                                                  \
        _Pragma("unroll")                                                              \
        for (int i = 0; i < 4; ++i) {                                                  \
            int row = bm0 + a_row + i * 32;                                            \
            if constexpr (XF16) {                                                      \
                if (row < M)                                                           \
                    aReg16[i] = *(const int4v*)(x16 + (size_t)row * K_DIM + (K0) + a_col); \
                else                                                                   \
                    aReg16[i] = (int4v){0, 0, 0, 0};                                   \
            } else {                                                                   \
                if (row < M)                                                           \
                    aReg32[i] = *(const f32x8*)(x32 + (size_t)row * K_DIM + (K0) + a_col); \
                else                                                                   \
                    aReg32[i] = (f32x8){0.f,0.f,0.f,0.f,0.f,0.f,0.f,0.f};              \
            }                                                                          \
        }                                                                              \
        bReg = *(const int4v*)(qw + (size_t)((K0) + b_krow) * WORDS_N + w0 + b_wq);    \
    }

    LOAD_TILE(0);

    const int NT = K_DIM / BK;  // 64
    for (int t = 0; t < NT; ++t) {
        const int k0 = t * BK;

        __syncthreads();   // previous iteration done reading LDS
        #pragma unroll
        for (int i = 0; i < 4; ++i) {
            if constexpr (XF16) {
                *(int4v*)&As[(a_row + i * 32) * ASTR + a_col] = aReg16[i];
            } else {
                f16x8 h;
                #pragma unroll
                for (int r = 0; r < 4; ++r) {
                    f16x2 p = __builtin_bit_cast(f16x2,
                        __builtin_amdgcn_cvt_pkrtz(aReg32[i][2*r], aReg32[i][2*r+1]));
                    h[2*r]   = p[0];
                    h[2*r+1] = p[1];
                }
                *(f16x8*)&As[(a_row + i * 32) * ASTR + a_col] = h;
            }
        }
        #pragma unroll
        for (int c = 0; c < 4; ++c)
            Wq[(b_wq + c) * WSTR + b_krow] = bReg[c];   // transposed: Wq[w][k]
        __syncthreads();   // tile visible

        if (t + 1 < NT) LOAD_TILE(k0 + BK);   // prefetch next tile into regs

        if ((t & 1) == 0) {   // group changes every 2 tiles (GROUP=128, BK=64)
            const int g = k0 >> 7;
            #pragma unroll
            for (int bn = 0; bn < 2; ++bn) {
                float s = sc[(size_t)g * N_DIM + bn0 + n_loc[bn]];
                int zq  = (qz[(size_t)g * WORDS_N + w0 + w_loc[bn]] >> shf[bn]) & 0xF;
                _Float16 sh = (_Float16)s;
                _Float16 nz = (_Float16)(-(float)zq * s);
                s2[bn] = (f16x2){sh, sh};
                c2[bn] = (f16x2){nz, nz};
            }
        }

        #pragma unroll
        for (int ks = 0; ks < 2; ++ks) {
            const int kk = ks * 32 + (lane >> 4) * 8;   // this lane's k-octet
            f16x8 af[8];
            #pragma unroll
            for (int am = 0; am < 8; ++am)
                af[am] = *(const f16x8*)&As[(am * 16 + (lane & 15)) * ASTR + kk];

            #pragma unroll
            for (int bn = 0; bn < 2; ++bn) {
                const int4v lo = *(const int4v*)&Wq[w_loc[bn] * WSTR + kk];
                const int4v hi = *(const int4v*)&Wq[w_loc[bn] * WSTR + kk + 4];
                f16x8 bf;
                f16x2 p;
                p = dq2(lo[0], lo[1], shf[bn], s2[bn], c2[bn]); bf[0]=p[0]; bf[1]=p[1];
                p = dq2(lo[2], lo[3], shf[bn], s2[bn], c2[bn]); bf[2]=p[0]; bf[3]=p[1];
                p = dq2(hi[0], hi[1], shf[bn], s2[bn], c2[bn]); bf[4]=p[0]; bf[5]=p[1];
                p = dq2(hi[2], hi[3], shf[bn], s2[bn], c2[bn]); bf[6]=p[0]; bf[7]=p[1];
                #pragma unroll
                for (int am = 0; am < 8; ++am)
                    acc[am][bn] = __builtin_amdgcn_mfma_f32_16x16x32_f16(
                        af[am], bf, acc[am][bn], 0, 0, 0);
            }
        }
    }

    // epilogue: C/D layout col=lane&15, row=(lane>>4)*4+r (m89-verified)
    #pragma unroll
    for (int bn = 0; bn < 2; ++bn) {
        const int col = bn0 + wn0 + bn * 16 + (lane & 15);
        const float b_f = bias[col];
        #pragma unroll
        for (int am = 0; am < 8; ++am) {
            const int row_base = bm0 + am * 16 + ((lane >> 4) << 2);
            #pragma unroll
            for (int r = 0; r < 4; ++r) {
                const int row = row_base + r;
                if (row < M)
                    out[(size_t)row * N_DIM + col] = acc[am][bn][r] + b_f;
            }
        }
    }
#undef LOAD_TILE
}

extern "C" void kernel_launch(void* const* d_in, const int* in_sizes, int n_in,
                              void* d_out, int out_size, void* d_ws, size_t ws_size,
                              hipStream_t stream) {
    const float* x    = (const float*)d_in[0];
    const int*   qw   = (const int*)d_in[1];
    const int*   qz   = (const int*)d_in[2];
    const float* sc   = (const float*)d_in[3];
    const float* bias = (const float*)d_in[4];
    float*       out  = (float*)d_out;

    const int M = in_sizes[0] / K_DIM;   // 2048 tokens
    dim3 grid(N_DIM / BN, (M + BM - 1) / BM);

    const size_t need = (size_t)M * K_DIM * 2;
    if (ws_size >= need) {
        ushort* xf = (ushort*)d_ws;
        int n8 = (M * K_DIM) / 8;
        cvt_x_kernel<<<dim3(2048), dim3(256), 0, stream>>>(x, xf, n8);
        awq_gemm_kernel<true><<<grid, dim3(256), 0, stream>>>(xf, qw, qz, sc, bias, out, M);
    } else {
        awq_gemm_kernel<false><<<grid, dim3(256), 0, stream>>>(x, qw, qz, sc, bias, out, M);
    }
}

// Round 7
// 267.690 us; speedup vs baseline: 1.5846x; 1.0266x over previous
//
#include <hip/hip_runtime.h>
#include <stdint.h>

#define K_DIM 4096
#define N_DIM 11008
#define WORDS_N 1376          // N_DIM / 8 packed words
#define BM 128
#define BN 256
#define BK 64
#define ASTR 72               // As row stride in fp16 elems (144B; even bank spread for b128)
#define WSTR 68               // Wq row stride in ints (272B: 16B-aligned, bank-spread)

typedef _Float16 f16x2 __attribute__((ext_vector_type(2)));
typedef _Float16 f16x8 __attribute__((ext_vector_type(8)));
typedef float    f32x4 __attribute__((ext_vector_type(4)));
typedef float    f32x8 __attribute__((ext_vector_type(8)));
typedef int      int4v __attribute__((ext_vector_type(4)));
typedef unsigned short ushort;
typedef unsigned int u32;

// two packed-word k-values -> half2 of dequantized weights for one column
// (q-z)*s via pk_fma(q, s, -zs); q built exactly via 0x6400 magic + pk_sub(1024)
__device__ __forceinline__ f16x2 dq2(int wa, int wb, int shf, f16x2 s2, f16x2 c2) {
    u32 t0 = ((u32)wa >> shf) & 0xFu;
    u32 t1 = ((u32)wb >> shf) & 0xFu;
    u32 h  = 0x64006400u | t0 | (t1 << 16);
    f16x2 q = __builtin_bit_cast(f16x2, h);
    q = q - (f16x2)((_Float16)1024.0f);   // exact: (1024+q) - 1024
    return q * s2 + c2;                    // v_pk_fma_f16
}

// ---- pre-pass: x f32 -> fp16 (values are exactly fp16-representable) ----
__global__ __launch_bounds__(256)
void cvt_x_kernel(const float* __restrict__ x, ushort* __restrict__ xf, int n8) {
    for (int i = blockIdx.x * 256 + threadIdx.x; i < n8; i += gridDim.x * 256) {
        f32x4 a = *(const f32x4*)(x + (size_t)i * 8);
        f32x4 b = *(const f32x4*)(x + (size_t)i * 8 + 4);
        int4v o;
        o[0] = __builtin_bit_cast(int, __builtin_amdgcn_cvt_pkrtz(a[0], a[1]));
        o[1] = __builtin_bit_cast(int, __builtin_amdgcn_cvt_pkrtz(a[2], a[3]));
        o[2] = __builtin_bit_cast(int, __builtin_amdgcn_cvt_pkrtz(b[0], b[1]));
        o[3] = __builtin_bit_cast(int, __builtin_amdgcn_cvt_pkrtz(b[2], b[3]));
        *(int4v*)(xf + (size_t)i * 8) = o;
    }
}

template <bool XF16>
__global__ __launch_bounds__(256, 2)
void awq_gemm_kernel(const void* __restrict__ xin,
                     const int* __restrict__ qw,
                     const int* __restrict__ qz,
                     const float* __restrict__ sc,
                     const float* __restrict__ bias,
                     float* __restrict__ out,
                     int M)
{
    __shared__ __align__(16) _Float16 As[BM * ASTR];  // 18432 B
    __shared__ __align__(16) int Wq[32 * WSTR];       // [word][k] transposed, 8704 B

    const int tid  = threadIdx.x;
    const int lane = tid & 63;
    const int wid  = tid >> 6;

    const int bn0 = blockIdx.x * BN;
    const int bm0 = blockIdx.y * BM;
    const int w0  = bn0 >> 3;            // first packed word col of this tile (32 words)

    // 1x4 wave grid: each wave owns all 128 rows x 64 distinct cols
    const int wn0 = wid * 64;

    // A staging: 4 rows of 8 fp16 (or 8 f32) per thread
    const int a_row = tid >> 3;          // 0..31 (+32*i)
    const int a_col = (tid & 7) * 8;

    // B raw staging: each thread two dwordx4 (words b_wg..+3 and b_wg+16..+19, one k-row)
    const int b_krow = tid >> 2;         // 0..63
    const int b_wg   = (tid & 3) * 4;    // 0,4,8,12

    // per-bn column constants (AWQ interleave vs ORDER_SHIFTS verified)
    int n_loc[4], w_loc[4], shf[4];
    #pragma unroll
    for (int bn = 0; bn < 4; ++bn) {
        n_loc[bn] = wn0 + bn * 16 + (lane & 15);     // 0..255 within block
        w_loc[bn] = n_loc[bn] >> 3;                  // 0..31
        int j = n_loc[bn] & 7;
        shf[bn] = ((j & 1) << 4) + ((j >> 1) << 2);  // j -> [0,16,4,20,8,24,12,28]
    }

    f16x2 s2[4], c2[4];   // scale and -(z*s) per owned column

    f32x4 acc[8][4];
    #pragma unroll
    for (int i = 0; i < 8; ++i)
        #pragma unroll
        for (int j = 0; j < 4; ++j)
            acc[i][j] = (f32x4){0.f, 0.f, 0.f, 0.f};

    int4v aReg16[4];
    f32x8 aReg32[4];
    int4v bReg[2];

    const ushort* x16 = (const ushort*)xin;
    const float*  x32 = (const float*)xin;

#define LOAD_TILE(K0)                                                                  \
    {                                                                                  \
        _Pragma("unroll")                                                              \
        for (int i = 0; i < 4; ++i) {                                                  \
            int row = bm0 + a_row + i * 32;                                            \
            if constexpr (XF16) {                                                      \
                if (row < M)                                                           \
                    aReg16[i] = *(const int4v*)(x16 + (size_t)row * K_DIM + (K0) + a_col); \
                else                                                                   \
                    aReg16[i] = (int4v){0, 0, 0, 0};                                   \
            } else {                                                                   \
                if (row < M)                                                           \
                    aReg32[i] = *(const f32x8*)(x32 + (size_t)row * K_DIM + (K0) + a_col); \
                else                                                                   \
                    aReg32[i] = (f32x8){0.f,0.f,0.f,0.f,0.f,0.f,0.f,0.f};              \
            }                                                                          \
        }                                                                              \
        bReg[0] = *(const int4v*)(qw + (size_t)((K0) + b_krow) * WORDS_N + w0 + b_wg);      \
        bReg[1] = *(const int4v*)(qw + (size_t)((K0) + b_krow) * WORDS_N + w0 + b_wg + 16); \
    }

    LOAD_TILE(0);

    const int NT = K_DIM / BK;  // 64
    for (int t = 0; t < NT; ++t) {
        const int k0 = t * BK;

        __syncthreads();   // previous iteration done reading LDS
        #pragma unroll
        for (int i = 0; i < 4; ++i) {
            if constexpr (XF16) {
                *(int4v*)&As[(a_row + i * 32) * ASTR + a_col] = aReg16[i];
            } else {
                f16x8 h;
                #pragma unroll
                for (int r = 0; r < 4; ++r) {
                    f16x2 p = __builtin_bit_cast(f16x2,
                        __builtin_amdgcn_cvt_pkrtz(aReg32[i][2*r], aReg32[i][2*r+1]));
                    h[2*r]   = p[0];
                    h[2*r+1] = p[1];
                }
                *(f16x8*)&As[(a_row + i * 32) * ASTR + a_col] = h;
            }
        }
        #pragma unroll
        for (int c = 0; c < 4; ++c) {
            Wq[(b_wg + c) * WSTR + b_krow]      = bReg[0][c];   // words 0..15
            Wq[(b_wg + 16 + c) * WSTR + b_krow] = bReg[1][c];   // words 16..31
        }
        __syncthreads();   // tile visible

        if (t + 1 < NT) LOAD_TILE(k0 + BK);   // prefetch next tile into regs

        if ((t & 1) == 0) {   // group changes every 2 tiles (GROUP=128, BK=64)
            const int g = k0 >> 7;
            #pragma unroll
            for (int bn = 0; bn < 4; ++bn) {
                float s = sc[(size_t)g * N_DIM + bn0 + n_loc[bn]];
                int zq  = (qz[(size_t)g * WORDS_N + w0 + w_loc[bn]] >> shf[bn]) & 0xF;
                _Float16 sh = (_Float16)s;
                _Float16 nz = (_Float16)(-(float)zq * s);
                s2[bn] = (f16x2){sh, sh};
                c2[bn] = (f16x2){nz, nz};
            }
        }

        #pragma unroll
        for (int ks = 0; ks < 2; ++ks) {
            const int kk = ks * 32 + (lane >> 4) * 8;   // this lane's k-octet
            f16x8 af[8];
            #pragma unroll
            for (int am = 0; am < 8; ++am)
                af[am] = *(const f16x8*)&As[(am * 16 + (lane & 15)) * ASTR + kk];

            #pragma unroll
            for (int bn = 0; bn < 4; ++bn) {
                const int4v lo = *(const int4v*)&Wq[w_loc[bn] * WSTR + kk];
                const int4v hi = *(const int4v*)&Wq[w_loc[bn] * WSTR + kk + 4];
                f16x8 bf;
                f16x2 p;
                p = dq2(lo[0], lo[1], shf[bn], s2[bn], c2[bn]); bf[0]=p[0]; bf[1]=p[1];
                p = dq2(lo[2], lo[3], shf[bn], s2[bn], c2[bn]); bf[2]=p[0]; bf[3]=p[1];
                p = dq2(hi[0], hi[1], shf[bn], s2[bn], c2[bn]); bf[4]=p[0]; bf[5]=p[1];
                p = dq2(hi[2], hi[3], shf[bn], s2[bn], c2[bn]); bf[6]=p[0]; bf[7]=p[1];
                #pragma unroll
                for (int am = 0; am < 8; ++am)
                    acc[am][bn] = __builtin_amdgcn_mfma_f32_16x16x32_f16(
                        af[am], bf, acc[am][bn], 0, 0, 0);
            }
        }
    }

    // epilogue: C/D layout col=lane&15, row=(lane>>4)*4+r (m89-verified)
    #pragma unroll
    for (int bn = 0; bn < 4; ++bn) {
        const int col = bn0 + wn0 + bn * 16 + (lane & 15);
        const float b_f = bias[col];
        #pragma unroll
        for (int am = 0; am < 8; ++am) {
            const int row_base = bm0 + am * 16 + ((lane >> 4) << 2);
            #pragma unroll
            for (int r = 0; r < 4; ++r) {
                const int row = row_base + r;
                if (row < M)
                    out[(size_t)row * N_DIM + col] = acc[am][bn][r] + b_f;
            }
        }
    }
#undef LOAD_TILE
}

extern "C" void kernel_launch(void* const* d_in, const int* in_sizes, int n_in,
                              void* d_out, int out_size, void* d_ws, size_t ws_size,
                              hipStream_t stream) {
    const float* x    = (const float*)d_in[0];
    const int*   qw   = (const int*)d_in[1];
    const int*   qz   = (const int*)d_in[2];
    const float* sc   = (const float*)d_in[3];
    const float* bias = (const float*)d_in[4];
    float*       out  = (float*)d_out;

    const int M = in_sizes[0] / K_DIM;   // 2048 tokens
    dim3 grid(N_DIM / BN, (M + BM - 1) / BM);   // 43 x 16

    const size_t need = (size_t)M * K_DIM * 2;
    if (ws_size >= need) {
        ushort* xf = (ushort*)d_ws;
        int n8 = (M * K_DIM) / 8;
        cvt_x_kernel<<<dim3(2048), dim3(256), 0, stream>>>(x, xf, n8);
        awq_gemm_kernel<true><<<grid, dim3(256), 0, stream>>>(xf, qw, qz, sc, bias, out, M);
    } else {
        awq_gemm_kernel<false><<<grid, dim3(256), 0, stream>>>(x, qw, qz, sc, bias, out, M);
    }
}